// Round 10
// baseline (175.118 us; speedup 1.0000x reference)
//
#include <hip/hip_runtime.h>

#define B_SZ 1024
#define S_SZ 200
#define D_SZ 64
#define NI_SZ 4
#define E_SZ 256

using u16 = unsigned short;
using u32 = unsigned int;
typedef short  sh4    __attribute__((ext_vector_type(4)));
typedef short  sh8    __attribute__((ext_vector_type(8)));
typedef __bf16 bf16x8 __attribute__((ext_vector_type(8)));
typedef float  f32x4  __attribute__((ext_vector_type(4)));

__device__ __forceinline__ u16 f2bf(float x) {          // RNE f32 -> bf16 bits
  u32 u = __float_as_uint(x);
  u += 0x7FFFu + ((u >> 16) & 1u);
  return (u16)(u >> 16);
}
__device__ __forceinline__ float bf2f(u16 h) {
  return __uint_as_float(((u32)h) << 16);
}
// swizzled LDS tile access: row-major [R][64] bf16 (128 B rows), byte ^= (row&7)<<4
__device__ __forceinline__ sh8 ldsr(const u16* arr, int row, int kshort) {
  const int idx = row * 64 + (kshort ^ ((row & 7) << 3));
  return *(const sh8*)(arr + idx);
}
__device__ __forceinline__ bf16x8 ldsw(const u16* arr, int row, int kshort) {
  return __builtin_bit_cast(bf16x8, ldsr(arr, row, kshort));
}
__device__ __forceinline__ void stsw(u16* arr, int row, int c, sh8 v) {
  *(sh8*)(arr + row * 64 + 8 * (c ^ (row & 7))) = v;
}
__device__ __forceinline__ sh8 cvt8(const float* __restrict__ src, float m) {
  const float4 a = *(const float4*)(src);
  const float4 d = *(const float4*)(src + 4);
  sh8 v;
  v[0] = (short)f2bf(a.x * m); v[1] = (short)f2bf(a.y * m);
  v[2] = (short)f2bf(a.z * m); v[3] = (short)f2bf(a.w * m);
  v[4] = (short)f2bf(d.x * m); v[5] = (short)f2bf(d.y * m);
  v[6] = (short)f2bf(d.z * m); v[7] = (short)f2bf(d.w * m);
  return v;
}

// ---------------- K1: fused profile + gather + adj MFMA; 2 blocks per b (mt split) ----------------
__global__ __launch_bounds__(256) void adj_kernel(
    const int* __restrict__ uid, const int* __restrict__ age,
    const int* __restrict__ gender, const int* __restrict__ occup,
    const float* __restrict__ U, const float* __restrict__ AT,
    const float* __restrict__ GT, const float* __restrict__ OT,
    const int* __restrict__ mid_his, const float* __restrict__ mask,
    const float* __restrict__ memb, float* __restrict__ adj)
{
  const int b    = blockIdx.x >> 1;
  const int half = blockIdx.x & 1;
  const int mt0 = half ? 7 : 0;
  const int mt1 = half ? 13 : 7;
  __shared__ u16   Hs[208 * 64];   // 26624 B, swizzled
  __shared__ float Ms[208];
  __shared__ int   midS[S_SZ];
  __shared__ float pS[D_SZ];
  const int tid = threadIdx.x;

  if (tid < 208) Ms[tid] = (tid < S_SZ) ? mask[b * S_SZ + tid] : 0.f;
  if (tid < S_SZ) midS[tid] = mid_his[b * S_SZ + tid];
  if (tid < D_SZ) {
    float v = U[(size_t)uid[b]     * D_SZ + tid]
            + GT[(size_t)gender[b] * D_SZ + tid]
            + AT[(size_t)age[b]    * D_SZ + tid]
            + OT[(size_t)occup[b]  * D_SZ + tid];
    pS[tid] = 0.25f * v;
  }
  __syncthreads();

  for (int idx = tid; idx < S_SZ * 8; idx += 256) {
    const int row = idx >> 3, c = idx & 7;
    const float m = Ms[row];
    sh8 v = {0, 0, 0, 0, 0, 0, 0, 0};
    if (m != 0.f) v = cvt8(memb + (size_t)midS[row] * D_SZ + c * 8, m);
    stsw(Hs, row, c, v);
  }
  if (tid < 64) {   // zero-pad rows 200..207
    sh8 z = {0,0,0,0,0,0,0,0};
    stsw(Hs, S_SZ + (tid >> 3), tid & 7, z);
  }
  __syncthreads();

  const int w = tid >> 6, l = tid & 63;
  const int lr = l & 15, lg = l >> 4;
  float pvA[8], pvB[8];
  #pragma unroll
  for (int j = 0; j < 8; j++) { pvA[j] = pS[lg * 8 + j]; pvB[j] = pS[32 + lg * 8 + j]; }

  float* outb = adj + (size_t)b * S_SZ * S_SZ;
  for (int mt = mt0; mt < mt1; mt++) {
    const int arow = mt * 16 + lr;
    const sh8 r0 = ldsr(Hs, arow, lg * 8);
    const sh8 r1 = ldsr(Hs, arow, 32 + lg * 8);
    sh8 h0, h1;
    #pragma unroll
    for (int j = 0; j < 8; j++) {
      h0[j] = (short)f2bf(bf2f((u16)r0[j]) * pvA[j]);
      h1[j] = (short)f2bf(bf2f((u16)r1[j]) * pvB[j]);
    }
    const bf16x8 a0 = __builtin_bit_cast(bf16x8, h0);
    const bf16x8 a1 = __builtin_bit_cast(bf16x8, h1);
    for (int nt = w; nt < 13; nt += 4) {
      const int brow = nt * 16 + lr;
      const bf16x8 b0 = ldsw(Hs, brow, lg * 8);
      const bf16x8 b1 = ldsw(Hs, brow, 32 + lg * 8);
      f32x4 acc = {0.f, 0.f, 0.f, 0.f};
      acc = __builtin_amdgcn_mfma_f32_16x16x32_bf16(a0, b0, acc, 0, 0, 0);
      acc = __builtin_amdgcn_mfma_f32_16x16x32_bf16(a1, b1, acc, 0, 0, 0);
      const int n = nt * 16 + lr;
      const float mj = Ms[n];
      #pragma unroll
      for (int rr = 0; rr < 4; rr++) {
        const int m = mt * 16 + lg * 4 + rr;
        if (m < S_SZ && n < S_SZ) {
          const float sg = 1.f / (1.f + __expf(-acc[rr]));
          outb[(size_t)m * S_SZ + n] = sg * Ms[m] * mj;
        }
      }
    }
  }
}

// ---------------- K2: hat via MFMA (A=W, B=item), e-split halves, masked-store skip ----------------
__global__ __launch_bounds__(256, 6) void hat_kernel(
    const int* __restrict__ mid_his, const float* __restrict__ mask,
    const float* __restrict__ memb, const float* __restrict__ WC,
    u16* __restrict__ hatb)
{
  // bid = t*256 + x*16 + eh*8 + r ; s = t*8 + r (32 blocks sharing s sit on one XCD)
  const int bid = blockIdx.x;
  const int s  = (bid >> 8) * 8 + (bid & 7);   // [0,200)
  const int eh = (bid >> 3) & 1;               // e-half
  const int b0 = ((bid >> 4) & 15) * 64;
  __shared__ u16 As[64 * 64];      // item rows, 8 KB
  __shared__ u16 Ws_[128 * 64];    // W[s] half, 16 KB
  __shared__ float mskS[64];
  const int tid = threadIdx.x;

  for (int idx = tid; idx < 64 * 8; idx += 256) {
    const int row = idx >> 3, c = idx & 7;
    const int bb = b0 + row;
    const float m = mask[bb * S_SZ + s];
    if (c == 0) mskS[row] = m;
    sh8 v = {0, 0, 0, 0, 0, 0, 0, 0};
    if (m != 0.f)
      v = cvt8(memb + (size_t)mid_his[bb * S_SZ + s] * D_SZ + c * 8, m);
    stsw(As, row, c, v);
  }
  for (int idx = tid; idx < 128 * 8; idx += 256) {
    const int row = idx >> 3, c = idx & 7;
    stsw(Ws_, row, c, cvt8(WC + ((size_t)s * E_SZ + eh * 128 + row) * D_SZ + c * 8, 1.f));
  }
  __syncthreads();

  const int w = tid >> 6, l = tid & 63;
  const int lr = l & 15, lg = l >> 4;

  f32x4 acc[2][4];                 // [me][nb]
  #pragma unroll
  for (int me = 0; me < 2; me++)
    #pragma unroll
    for (int nb = 0; nb < 4; nb++) acc[me][nb] = (f32x4){0.f, 0.f, 0.f, 0.f};

  #pragma unroll
  for (int ks = 0; ks < 2; ks++) {
    bf16x8 wf[2], itf[4];
    #pragma unroll
    for (int me = 0; me < 2; me++)
      wf[me] = ldsw(Ws_, w * 32 + me * 16 + lr, ks * 32 + lg * 8);
    #pragma unroll
    for (int nb = 0; nb < 4; nb++)
      itf[nb] = ldsw(As, nb * 16 + lr, ks * 32 + lg * 8);
    #pragma unroll
    for (int me = 0; me < 2; me++)
      #pragma unroll
      for (int nb = 0; nb < 4; nb++)
        acc[me][nb] = __builtin_amdgcn_mfma_f32_16x16x32_bf16(wf[me], itf[nb], acc[me][nb], 0, 0, 0);
  }

  // e_global = eh*128 + w*32 + me*16 + lg*4 + rr ; kc = e>>6, d = e&63
  #pragma unroll
  for (int nb = 0; nb < 4; nb++) {
    const int bb = b0 + nb * 16 + lr;
    const bool live = (mskS[nb * 16 + lr] != 0.f);
    #pragma unroll
    for (int me = 0; me < 2; me++) {
      const int eg = eh * 128 + w * 32 + me * 16;
      const int kc = eg >> 6;
      const int d0 = (eg & 63) + lg * 4;
      if (live) {
        sh4 v;
        v[0] = (short)f2bf(acc[me][nb][0]);
        v[1] = (short)f2bf(acc[me][nb][1]);
        v[2] = (short)f2bf(acc[me][nb][2]);
        v[3] = (short)f2bf(acc[me][nb][3]);
        *(sh4*)(hatb + (((size_t)bb * NI_SZ + kc) * S_SZ + s) * D_SZ + d0) = v;
      }
    }
  }
}

// ---------------- K3: dynamic routing; masked rows never fetched (scalar-branch skip) ----------------
__device__ __forceinline__ float rlane(float v, int l) {
  return __int_as_float(__builtin_amdgcn_readlane(__float_as_int(v), l));
}

__global__ __launch_bounds__(1024, 4) void route_kernel(
    const u16* __restrict__ hatb, const float* __restrict__ mask,
    float* __restrict__ out)
{
  const int b = blockIdx.x;
  const int t = threadIdx.x;
  const int w = t >> 6, lane = t & 63;
  const int k = w >> 2, q = w & 3;
  __shared__ float cwS[NI_SZ][212];
  __shared__ float partS[NI_SZ][4][D_SZ];

  const float msv = (lane < 50) ? mask[b * S_SZ + q * 50 + lane] : 0.f;

  float hr[50];
  const u16* hg = hatb + (((size_t)b * NI_SZ + k) * S_SZ + q * 50) * D_SZ + lane;
  #pragma unroll
  for (int j = 0; j < 50; j++) {
    // mask for position j is wave-uniform -> scalar branch skips the fetch entirely
    const u32 hmu = __builtin_amdgcn_readfirstlane(__float_as_uint(rlane(msv, j)));
    float v = 0.f;
    if (hmu != 0u) v = bf2f(hg[j * D_SZ]);
    hr[j] = v;
  }
  #pragma unroll
  for (int j = 0; j < 50; j++) asm volatile("" : "+v"(hr[j]));

  const int jj = __brev(lane) >> 26;

  for (int iter = 0; iter < 3; ++iter) {
    float swv;
    if (iter == 0) {
      swv = 0.25f * msv;
    } else {
      const int sidx = q * 50 + (lane < 50 ? lane : 49);
      const float a0 = cwS[0][sidx], a1 = cwS[1][sidx],
                  a2 = cwS[2][sidx], a3 = cwS[3][sidx];
      const float mx = fmaxf(fmaxf(a0, a1), fmaxf(a2, a3));
      const float e0 = __expf(a0 - mx), e1 = __expf(a1 - mx),
                  e2 = __expf(a2 - mx), e3 = __expf(a3 - mx);
      const float ek = (k == 0) ? e0 : (k == 1) ? e1 : (k == 2) ? e2 : e3;
      const float inv = 1.f / (e0 + e1 + e2 + e3);
      swv = (msv == 0.f) ? 0.f : ek * inv;
    }

    float c0 = 0.f, c1 = 0.f, c2 = 0.f, c3 = 0.f;
    #pragma unroll
    for (int j = 0; j < 48; j += 4) {
      c0 = fmaf(rlane(swv, j + 0), hr[j + 0], c0);
      c1 = fmaf(rlane(swv, j + 1), hr[j + 1], c1);
      c2 = fmaf(rlane(swv, j + 2), hr[j + 2], c2);
      c3 = fmaf(rlane(swv, j + 3), hr[j + 3], c3);
    }
    c0 = fmaf(rlane(swv, 48), hr[48], c0);
    c1 = fmaf(rlane(swv, 49), hr[49], c1);
    partS[k][q][lane] = (c0 + c2) + (c1 + c3);
    __syncthreads();

    const float cap = partS[k][0][lane] + partS[k][1][lane]
                    + partS[k][2][lane] + partS[k][3][lane];
    float n = cap * cap;
    #pragma unroll
    for (int off = 32; off; off >>= 1) n += __shfl_xor(n, off);
    const float f = n / (1.f + n) * rsqrtf(n + 1e-9f);
    const float capd = cap * f;

    if (iter < 2) {
      float p[32];
      {
        const int bit = lane & 1;
        #pragma unroll
        for (int j = 0; j < 32; j++) {
          const float lo = hr[j] * capd;
          const float hi = (j + 32 < 50) ? hr[j + 32] * capd : 0.f;
          const float send = bit ? lo : hi;
          const float keep = bit ? hi : lo;
          p[j] = keep + __shfl_xor(send, 1);
        }
      }
      #pragma unroll
      for (int rr = 1; rr < 6; rr++) {
        const int dist = 1 << rr;
        const int half = 32 >> rr;
        const int bit = (lane >> rr) & 1;
        #pragma unroll
        for (int j = 0; j < 32; j++) {
          if (j < half) {
            const float send = bit ? p[j] : p[j + half];
            const float keep = bit ? p[j + half] : p[j];
            p[j] = keep + __shfl_xor(send, dist);
          }
        }
      }
      if (jj < 50) {
        if (iter == 0) cwS[k][q * 50 + jj] = p[0];
        else           cwS[k][q * 50 + jj] += p[0];
      }
      __syncthreads();
    } else if (q == 0) {
      out[((size_t)b * NI_SZ + k) * D_SZ + lane] = capd;
    }
  }
}

extern "C" void kernel_launch(void* const* d_in, const int* in_sizes, int n_in,
                              void* d_out, int out_size, void* d_ws, size_t ws_size,
                              hipStream_t stream)
{
  const int*   uid     = (const int*)d_in[0];
  const int*   age     = (const int*)d_in[1];
  const int*   gender  = (const int*)d_in[2];
  const int*   occup   = (const int*)d_in[3];
  const int*   mid_his = (const int*)d_in[4];
  const float* mask    = (const float*)d_in[5];
  const float* U       = (const float*)d_in[6];
  const float* AT      = (const float*)d_in[7];
  const float* GT      = (const float*)d_in[8];
  const float* OT      = (const float*)d_in[9];
  const float* ME      = (const float*)d_in[10];
  const float* WC      = (const float*)d_in[11];

  float* out  = (float*)d_out;
  float* adj  = out + B_SZ * NI_SZ * D_SZ;

  u16* hatb = (u16*)d_ws;                      // 104.9 MB

  adj_kernel<<<2 * B_SZ, 256, 0, stream>>>(uid, age, gender, occup, U, AT, GT, OT,
                                           mid_his, mask, ME, adj);
  hat_kernel<<<6400, 256, 0, stream>>>(mid_his, mask, ME, WC, hatb);
  route_kernel<<<B_SZ, 1024, 0, stream>>>(hatb, mask, out);
}

// Round 11
// 147.195 us; speedup vs baseline: 1.1897x; 1.1897x over previous
//
#include <hip/hip_runtime.h>

#define B_SZ 1024
#define S_SZ 200
#define D_SZ 64
#define NI_SZ 4
#define E_SZ 256

using u16 = unsigned short;
using u32 = unsigned int;
typedef short  sh4    __attribute__((ext_vector_type(4)));
typedef short  sh8    __attribute__((ext_vector_type(8)));
typedef __bf16 bf16x8 __attribute__((ext_vector_type(8)));
typedef float  f32x4  __attribute__((ext_vector_type(4)));

__device__ __forceinline__ u16 f2bf(float x) {          // RNE f32 -> bf16 bits
  u32 u = __float_as_uint(x);
  u += 0x7FFFu + ((u >> 16) & 1u);
  return (u16)(u >> 16);
}
__device__ __forceinline__ float bf2f(u16 h) {
  return __uint_as_float(((u32)h) << 16);
}
// swizzled LDS tile access: row-major [R][64] bf16 (128 B rows), byte ^= (row&7)<<4
__device__ __forceinline__ sh8 ldsr(const u16* arr, int row, int kshort) {
  const int idx = row * 64 + (kshort ^ ((row & 7) << 3));
  return *(const sh8*)(arr + idx);
}
__device__ __forceinline__ bf16x8 ldsw(const u16* arr, int row, int kshort) {
  return __builtin_bit_cast(bf16x8, ldsr(arr, row, kshort));
}
__device__ __forceinline__ void stsw(u16* arr, int row, int c, sh8 v) {
  *(sh8*)(arr + row * 64 + 8 * (c ^ (row & 7))) = v;
}
__device__ __forceinline__ sh8 cvt8(const float* __restrict__ src, float m) {
  const float4 a = *(const float4*)(src);
  const float4 d = *(const float4*)(src + 4);
  sh8 v;
  v[0] = (short)f2bf(a.x * m); v[1] = (short)f2bf(a.y * m);
  v[2] = (short)f2bf(a.z * m); v[3] = (short)f2bf(a.w * m);
  v[4] = (short)f2bf(d.x * m); v[5] = (short)f2bf(d.y * m);
  v[6] = (short)f2bf(d.z * m); v[7] = (short)f2bf(d.w * m);
  return v;
}

// ---------------- K1: fused profile + gather + adj MFMA; 512 threads (8 waves) per b ----------------
__global__ __launch_bounds__(512) void adj_kernel(
    const int* __restrict__ uid, const int* __restrict__ age,
    const int* __restrict__ gender, const int* __restrict__ occup,
    const float* __restrict__ U, const float* __restrict__ AT,
    const float* __restrict__ GT, const float* __restrict__ OT,
    const int* __restrict__ mid_his, const float* __restrict__ mask,
    const float* __restrict__ memb, float* __restrict__ adj)
{
  const int b = blockIdx.x;
  __shared__ u16   Hs[208 * 64];   // 26624 B, swizzled
  __shared__ float Ms[208];
  __shared__ int   midS[S_SZ];
  __shared__ float pS[D_SZ];
  const int tid = threadIdx.x;

  if (tid < 208) Ms[tid] = (tid < S_SZ) ? mask[b * S_SZ + tid] : 0.f;
  if (tid < S_SZ) midS[tid] = mid_his[b * S_SZ + tid];
  if (tid < D_SZ) {
    float v = U[(size_t)uid[b]     * D_SZ + tid]
            + GT[(size_t)gender[b] * D_SZ + tid]
            + AT[(size_t)age[b]    * D_SZ + tid]
            + OT[(size_t)occup[b]  * D_SZ + tid];
    pS[tid] = 0.25f * v;
  }
  __syncthreads();

  for (int idx = tid; idx < S_SZ * 8; idx += 512) {
    const int row = idx >> 3, c = idx & 7;
    const float m = Ms[row];
    sh8 v = {0, 0, 0, 0, 0, 0, 0, 0};
    if (m != 0.f) v = cvt8(memb + (size_t)midS[row] * D_SZ + c * 8, m);
    stsw(Hs, row, c, v);
  }
  if (tid < 64) {   // zero-pad rows 200..207
    sh8 z = {0,0,0,0,0,0,0,0};
    stsw(Hs, S_SZ + (tid >> 3), tid & 7, z);
  }
  __syncthreads();

  const int w = tid >> 6, l = tid & 63;   // w in [0,8)
  const int lr = l & 15, lg = l >> 4;
  float pvA[8], pvB[8];
  #pragma unroll
  for (int j = 0; j < 8; j++) { pvA[j] = pS[lg * 8 + j]; pvB[j] = pS[32 + lg * 8 + j]; }

  float* outb = adj + (size_t)b * S_SZ * S_SZ;
  for (int mt = 0; mt < 13; mt++) {
    const int arow = mt * 16 + lr;
    const sh8 r0 = ldsr(Hs, arow, lg * 8);
    const sh8 r1 = ldsr(Hs, arow, 32 + lg * 8);
    sh8 h0, h1;
    #pragma unroll
    for (int j = 0; j < 8; j++) {
      h0[j] = (short)f2bf(bf2f((u16)r0[j]) * pvA[j]);
      h1[j] = (short)f2bf(bf2f((u16)r1[j]) * pvB[j]);
    }
    const bf16x8 a0 = __builtin_bit_cast(bf16x8, h0);
    const bf16x8 a1 = __builtin_bit_cast(bf16x8, h1);
    for (int nt = w; nt < 13; nt += 8) {
      const int brow = nt * 16 + lr;
      const bf16x8 b0 = ldsw(Hs, brow, lg * 8);
      const bf16x8 b1 = ldsw(Hs, brow, 32 + lg * 8);
      f32x4 acc = {0.f, 0.f, 0.f, 0.f};
      acc = __builtin_amdgcn_mfma_f32_16x16x32_bf16(a0, b0, acc, 0, 0, 0);
      acc = __builtin_amdgcn_mfma_f32_16x16x32_bf16(a1, b1, acc, 0, 0, 0);
      const int n = nt * 16 + lr;
      const float mj = Ms[n];
      #pragma unroll
      for (int rr = 0; rr < 4; rr++) {
        const int m = mt * 16 + lg * 4 + rr;
        if (m < S_SZ && n < S_SZ) {
          const float sg = 1.f / (1.f + __expf(-acc[rr]));
          outb[(size_t)m * S_SZ + n] = sg * Ms[m] * mj;
        }
      }
    }
  }
}

// ---------------- K2: hat via MFMA (A=W, B=item), e-split halves, masked-store skip ----------------
__global__ __launch_bounds__(256, 6) void hat_kernel(
    const int* __restrict__ mid_his, const float* __restrict__ mask,
    const float* __restrict__ memb, const float* __restrict__ WC,
    u16* __restrict__ hatb)
{
  // bid = t*256 + x*16 + eh*8 + r ; s = t*8 + r (32 blocks sharing s sit on one XCD)
  const int bid = blockIdx.x;
  const int s  = (bid >> 8) * 8 + (bid & 7);   // [0,200)
  const int eh = (bid >> 3) & 1;               // e-half
  const int b0 = ((bid >> 4) & 15) * 64;
  __shared__ u16 As[64 * 64];      // item rows, 8 KB
  __shared__ u16 Ws_[128 * 64];    // W[s] half, 16 KB
  __shared__ float mskS[64];
  const int tid = threadIdx.x;

  for (int idx = tid; idx < 64 * 8; idx += 256) {
    const int row = idx >> 3, c = idx & 7;
    const int bb = b0 + row;
    const float m = mask[bb * S_SZ + s];
    if (c == 0) mskS[row] = m;
    sh8 v = {0, 0, 0, 0, 0, 0, 0, 0};
    if (m != 0.f)
      v = cvt8(memb + (size_t)mid_his[bb * S_SZ + s] * D_SZ + c * 8, m);
    stsw(As, row, c, v);
  }
  for (int idx = tid; idx < 128 * 8; idx += 256) {
    const int row = idx >> 3, c = idx & 7;
    stsw(Ws_, row, c, cvt8(WC + ((size_t)s * E_SZ + eh * 128 + row) * D_SZ + c * 8, 1.f));
  }
  __syncthreads();

  const int w = tid >> 6, l = tid & 63;
  const int lr = l & 15, lg = l >> 4;

  f32x4 acc[2][4];                 // [me][nb]
  #pragma unroll
  for (int me = 0; me < 2; me++)
    #pragma unroll
    for (int nb = 0; nb < 4; nb++) acc[me][nb] = (f32x4){0.f, 0.f, 0.f, 0.f};

  #pragma unroll
  for (int ks = 0; ks < 2; ks++) {
    bf16x8 wf[2], itf[4];
    #pragma unroll
    for (int me = 0; me < 2; me++)
      wf[me] = ldsw(Ws_, w * 32 + me * 16 + lr, ks * 32 + lg * 8);
    #pragma unroll
    for (int nb = 0; nb < 4; nb++)
      itf[nb] = ldsw(As, nb * 16 + lr, ks * 32 + lg * 8);
    #pragma unroll
    for (int me = 0; me < 2; me++)
      #pragma unroll
      for (int nb = 0; nb < 4; nb++)
        acc[me][nb] = __builtin_amdgcn_mfma_f32_16x16x32_bf16(wf[me], itf[nb], acc[me][nb], 0, 0, 0);
  }

  // e_global = eh*128 + w*32 + me*16 + lg*4 + rr ; kc = e>>6, d = e&63
  #pragma unroll
  for (int nb = 0; nb < 4; nb++) {
    const int bb = b0 + nb * 16 + lr;
    const bool live = (mskS[nb * 16 + lr] != 0.f);
    #pragma unroll
    for (int me = 0; me < 2; me++) {
      const int eg = eh * 128 + w * 32 + me * 16;
      const int kc = eg >> 6;
      const int d0 = (eg & 63) + lg * 4;
      if (live) {
        sh4 v;
        v[0] = (short)f2bf(acc[me][nb][0]);
        v[1] = (short)f2bf(acc[me][nb][1]);
        v[2] = (short)f2bf(acc[me][nb][2]);
        v[3] = (short)f2bf(acc[me][nb][3]);
        *(sh4*)(hatb + (((size_t)bb * NI_SZ + kc) * S_SZ + s) * D_SZ + d0) = v;
      }
    }
  }
}

// ---------------- K3: dynamic routing (bf16 hat, register-resident, masked-hr cleanse) ----------------
__device__ __forceinline__ float rlane(float v, int l) {
  return __int_as_float(__builtin_amdgcn_readlane(__float_as_int(v), l));
}

__global__ __launch_bounds__(1024, 4) void route_kernel(
    const u16* __restrict__ hatb, const float* __restrict__ mask,
    float* __restrict__ out)
{
  const int b = blockIdx.x;
  const int t = threadIdx.x;
  const int w = t >> 6, lane = t & 63;
  const int k = w >> 2, q = w & 3;
  __shared__ float cwS[NI_SZ][212];
  __shared__ float partS[NI_SZ][4][D_SZ];

  const float msv = (lane < 50) ? mask[b * S_SZ + q * 50 + lane] : 0.f;

  float hr[50];
  const u16* hg = hatb + (((size_t)b * NI_SZ + k) * S_SZ + q * 50) * D_SZ + lane;
  #pragma unroll
  for (int j = 0; j < 50; j++) hr[j] = bf2f(hg[j * D_SZ]);
  // masked positions were never written by hat_kernel -> force exact zeros
  #pragma unroll
  for (int j = 0; j < 50; j++) {
    const float hm = rlane(msv, j);
    hr[j] = (hm != 0.f) ? hr[j] : 0.f;
  }
  #pragma unroll
  for (int j = 0; j < 50; j++) asm volatile("" : "+v"(hr[j]));

  const int jj = __brev(lane) >> 26;

  for (int iter = 0; iter < 3; ++iter) {
    float swv;
    if (iter == 0) {
      swv = 0.25f * msv;
    } else {
      const int sidx = q * 50 + (lane < 50 ? lane : 49);
      const float a0 = cwS[0][sidx], a1 = cwS[1][sidx],
                  a2 = cwS[2][sidx], a3 = cwS[3][sidx];
      const float mx = fmaxf(fmaxf(a0, a1), fmaxf(a2, a3));
      const float e0 = __expf(a0 - mx), e1 = __expf(a1 - mx),
                  e2 = __expf(a2 - mx), e3 = __expf(a3 - mx);
      const float ek = (k == 0) ? e0 : (k == 1) ? e1 : (k == 2) ? e2 : e3;
      const float inv = 1.f / (e0 + e1 + e2 + e3);
      swv = (msv == 0.f) ? 0.f : ek * inv;
    }

    float c0 = 0.f, c1 = 0.f, c2 = 0.f, c3 = 0.f;
    #pragma unroll
    for (int j = 0; j < 48; j += 4) {
      c0 = fmaf(rlane(swv, j + 0), hr[j + 0], c0);
      c1 = fmaf(rlane(swv, j + 1), hr[j + 1], c1);
      c2 = fmaf(rlane(swv, j + 2), hr[j + 2], c2);
      c3 = fmaf(rlane(swv, j + 3), hr[j + 3], c3);
    }
    c0 = fmaf(rlane(swv, 48), hr[48], c0);
    c1 = fmaf(rlane(swv, 49), hr[49], c1);
    partS[k][q][lane] = (c0 + c2) + (c1 + c3);
    __syncthreads();

    const float cap = partS[k][0][lane] + partS[k][1][lane]
                    + partS[k][2][lane] + partS[k][3][lane];
    float n = cap * cap;
    #pragma unroll
    for (int off = 32; off; off >>= 1) n += __shfl_xor(n, off);
    const float f = n / (1.f + n) * rsqrtf(n + 1e-9f);
    const float capd = cap * f;

    if (iter < 2) {
      float p[32];
      {
        const int bit = lane & 1;
        #pragma unroll
        for (int j = 0; j < 32; j++) {
          const float lo = hr[j] * capd;
          const float hi = (j + 32 < 50) ? hr[j + 32] * capd : 0.f;
          const float send = bit ? lo : hi;
          const float keep = bit ? hi : lo;
          p[j] = keep + __shfl_xor(send, 1);
        }
      }
      #pragma unroll
      for (int rr = 1; rr < 6; rr++) {
        const int dist = 1 << rr;
        const int half = 32 >> rr;
        const int bit = (lane >> rr) & 1;
        #pragma unroll
        for (int j = 0; j < 32; j++) {
          if (j < half) {
            const float send = bit ? p[j] : p[j + half];
            const float keep = bit ? p[j + half] : p[j];
            p[j] = keep + __shfl_xor(send, dist);
          }
        }
      }
      if (jj < 50) {
        if (iter == 0) cwS[k][q * 50 + jj] = p[0];
        else           cwS[k][q * 50 + jj] += p[0];
      }
      __syncthreads();
    } else if (q == 0) {
      out[((size_t)b * NI_SZ + k) * D_SZ + lane] = capd;
    }
  }
}

extern "C" void kernel_launch(void* const* d_in, const int* in_sizes, int n_in,
                              void* d_out, int out_size, void* d_ws, size_t ws_size,
                              hipStream_t stream)
{
  const int*   uid     = (const int*)d_in[0];
  const int*   age     = (const int*)d_in[1];
  const int*   gender  = (const int*)d_in[2];
  const int*   occup   = (const int*)d_in[3];
  const int*   mid_his = (const int*)d_in[4];
  const float* mask    = (const float*)d_in[5];
  const float* U       = (const float*)d_in[6];
  const float* AT      = (const float*)d_in[7];
  const float* GT      = (const float*)d_in[8];
  const float* OT      = (const float*)d_in[9];
  const float* ME      = (const float*)d_in[10];
  const float* WC      = (const float*)d_in[11];

  float* out  = (float*)d_out;
  float* adj  = out + B_SZ * NI_SZ * D_SZ;

  u16* hatb = (u16*)d_ws;                      // 104.9 MB

  adj_kernel<<<B_SZ, 512, 0, stream>>>(uid, age, gender, occup, U, AT, GT, OT,
                                       mid_his, mask, ME, adj);
  hat_kernel<<<6400, 256, 0, stream>>>(mid_his, mask, ME, WC, hatb);
  route_kernel<<<B_SZ, 1024, 0, stream>>>(hatb, mask, out);
}

// Round 12
// 136.317 us; speedup vs baseline: 1.2846x; 1.0798x over previous
//
#include <hip/hip_runtime.h>

#define B_SZ 1024
#define S_SZ 200
#define D_SZ 64
#define NI_SZ 4
#define E_SZ 256

using u16 = unsigned short;
using u32 = unsigned int;
typedef short  sh4    __attribute__((ext_vector_type(4)));
typedef short  sh8    __attribute__((ext_vector_type(8)));
typedef __bf16 bf16x8 __attribute__((ext_vector_type(8)));
typedef float  f32x4  __attribute__((ext_vector_type(4)));

__device__ __forceinline__ u16 f2bf(float x) {          // RNE f32 -> bf16 bits
  u32 u = __float_as_uint(x);
  u += 0x7FFFu + ((u >> 16) & 1u);
  return (u16)(u >> 16);
}
__device__ __forceinline__ float bf2f(u16 h) {
  return __uint_as_float(((u32)h) << 16);
}
// swizzled LDS tile access: row-major [R][64] bf16 (128 B rows), byte ^= (row&7)<<4
__device__ __forceinline__ sh8 ldsr(const u16* arr, int row, int kshort) {
  const int idx = row * 64 + (kshort ^ ((row & 7) << 3));
  return *(const sh8*)(arr + idx);
}
__device__ __forceinline__ bf16x8 ldsw(const u16* arr, int row, int kshort) {
  return __builtin_bit_cast(bf16x8, ldsr(arr, row, kshort));
}
__device__ __forceinline__ void stsw(u16* arr, int row, int c, sh8 v) {
  *(sh8*)(arr + row * 64 + 8 * (c ^ (row & 7))) = v;
}
__device__ __forceinline__ sh8 cvt8(const float* __restrict__ src, float m) {
  const float4 a = *(const float4*)(src);
  const float4 d = *(const float4*)(src + 4);
  sh8 v;
  v[0] = (short)f2bf(a.x * m); v[1] = (short)f2bf(a.y * m);
  v[2] = (short)f2bf(a.z * m); v[3] = (short)f2bf(a.w * m);
  v[4] = (short)f2bf(d.x * m); v[5] = (short)f2bf(d.y * m);
  v[6] = (short)f2bf(d.z * m); v[7] = (short)f2bf(d.w * m);
  return v;
}

// ---------------- K1: fused profile + gather + adj MFMA (R9 form: 256 thr, 1 block/b) ----------------
__global__ __launch_bounds__(256) void adj_kernel(
    const int* __restrict__ uid, const int* __restrict__ age,
    const int* __restrict__ gender, const int* __restrict__ occup,
    const float* __restrict__ U, const float* __restrict__ AT,
    const float* __restrict__ GT, const float* __restrict__ OT,
    const int* __restrict__ mid_his, const float* __restrict__ mask,
    const float* __restrict__ memb, float* __restrict__ adj)
{
  const int b = blockIdx.x;
  __shared__ u16   Hs[208 * 64];   // 26624 B, swizzled
  __shared__ float Ms[208];
  __shared__ int   midS[S_SZ];
  __shared__ float pS[D_SZ];
  const int tid = threadIdx.x;

  if (tid < 208) Ms[tid] = (tid < S_SZ) ? mask[b * S_SZ + tid] : 0.f;
  if (tid < S_SZ) midS[tid] = mid_his[b * S_SZ + tid];
  if (tid < D_SZ) {
    float v = U[(size_t)uid[b]     * D_SZ + tid]
            + GT[(size_t)gender[b] * D_SZ + tid]
            + AT[(size_t)age[b]    * D_SZ + tid]
            + OT[(size_t)occup[b]  * D_SZ + tid];
    pS[tid] = 0.25f * v;
  }
  __syncthreads();

  for (int idx = tid; idx < S_SZ * 8; idx += 256) {
    const int row = idx >> 3, c = idx & 7;
    const float m = Ms[row];
    sh8 v = {0, 0, 0, 0, 0, 0, 0, 0};
    if (m != 0.f) v = cvt8(memb + (size_t)midS[row] * D_SZ + c * 8, m);
    stsw(Hs, row, c, v);
  }
  if (tid < 64) {   // zero-pad rows 200..207
    sh8 z = {0,0,0,0,0,0,0,0};
    stsw(Hs, S_SZ + (tid >> 3), tid & 7, z);
  }
  __syncthreads();

  const int w = tid >> 6, l = tid & 63;
  const int lr = l & 15, lg = l >> 4;
  float pvA[8], pvB[8];
  #pragma unroll
  for (int j = 0; j < 8; j++) { pvA[j] = pS[lg * 8 + j]; pvB[j] = pS[32 + lg * 8 + j]; }

  float* outb = adj + (size_t)b * S_SZ * S_SZ;
  for (int mt = 0; mt < 13; mt++) {
    const int arow = mt * 16 + lr;
    const sh8 r0 = ldsr(Hs, arow, lg * 8);
    const sh8 r1 = ldsr(Hs, arow, 32 + lg * 8);
    sh8 h0, h1;
    #pragma unroll
    for (int j = 0; j < 8; j++) {
      h0[j] = (short)f2bf(bf2f((u16)r0[j]) * pvA[j]);
      h1[j] = (short)f2bf(bf2f((u16)r1[j]) * pvB[j]);
    }
    const bf16x8 a0 = __builtin_bit_cast(bf16x8, h0);
    const bf16x8 a1 = __builtin_bit_cast(bf16x8, h1);
    for (int nt = w; nt < 13; nt += 4) {
      const int brow = nt * 16 + lr;
      const bf16x8 b0 = ldsw(Hs, brow, lg * 8);
      const bf16x8 b1 = ldsw(Hs, brow, 32 + lg * 8);
      f32x4 acc = {0.f, 0.f, 0.f, 0.f};
      acc = __builtin_amdgcn_mfma_f32_16x16x32_bf16(a0, b0, acc, 0, 0, 0);
      acc = __builtin_amdgcn_mfma_f32_16x16x32_bf16(a1, b1, acc, 0, 0, 0);
      const int n = nt * 16 + lr;
      const float mj = Ms[n];
      #pragma unroll
      for (int rr = 0; rr < 4; rr++) {
        const int m = mt * 16 + lg * 4 + rr;
        if (m < S_SZ && n < S_SZ) {
          const float sg = 1.f / (1.f + __expf(-acc[rr]));
          outb[(size_t)m * S_SZ + n] = sg * Ms[m] * mj;
        }
      }
    }
  }
}

// ---------------- K2: hat via MFMA (A=W, B=item), e-split halves, masked-store skip ----------------
__global__ __launch_bounds__(256, 6) void hat_kernel(
    const int* __restrict__ mid_his, const float* __restrict__ mask,
    const float* __restrict__ memb, const float* __restrict__ WC,
    u16* __restrict__ hatb)
{
  // bid = t*256 + x*16 + eh*8 + r ; s = t*8 + r (32 blocks sharing s sit on one XCD)
  const int bid = blockIdx.x;
  const int s  = (bid >> 8) * 8 + (bid & 7);   // [0,200)
  const int eh = (bid >> 3) & 1;               // e-half
  const int b0 = ((bid >> 4) & 15) * 64;
  __shared__ u16 As[64 * 64];      // item rows, 8 KB
  __shared__ u16 Ws_[128 * 64];    // W[s] half, 16 KB
  __shared__ float mskS[64];
  const int tid = threadIdx.x;

  for (int idx = tid; idx < 64 * 8; idx += 256) {
    const int row = idx >> 3, c = idx & 7;
    const int bb = b0 + row;
    const float m = mask[bb * S_SZ + s];
    if (c == 0) mskS[row] = m;
    sh8 v = {0, 0, 0, 0, 0, 0, 0, 0};
    if (m != 0.f)
      v = cvt8(memb + (size_t)mid_his[bb * S_SZ + s] * D_SZ + c * 8, m);
    stsw(As, row, c, v);
  }
  for (int idx = tid; idx < 128 * 8; idx += 256) {
    const int row = idx >> 3, c = idx & 7;
    stsw(Ws_, row, c, cvt8(WC + ((size_t)s * E_SZ + eh * 128 + row) * D_SZ + c * 8, 1.f));
  }
  __syncthreads();

  const int w = tid >> 6, l = tid & 63;
  const int lr = l & 15, lg = l >> 4;

  f32x4 acc[2][4];                 // [me][nb]
  #pragma unroll
  for (int me = 0; me < 2; me++)
    #pragma unroll
    for (int nb = 0; nb < 4; nb++) acc[me][nb] = (f32x4){0.f, 0.f, 0.f, 0.f};

  #pragma unroll
  for (int ks = 0; ks < 2; ks++) {
    bf16x8 wf[2], itf[4];
    #pragma unroll
    for (int me = 0; me < 2; me++)
      wf[me] = ldsw(Ws_, w * 32 + me * 16 + lr, ks * 32 + lg * 8);
    #pragma unroll
    for (int nb = 0; nb < 4; nb++)
      itf[nb] = ldsw(As, nb * 16 + lr, ks * 32 + lg * 8);
    #pragma unroll
    for (int me = 0; me < 2; me++)
      #pragma unroll
      for (int nb = 0; nb < 4; nb++)
        acc[me][nb] = __builtin_amdgcn_mfma_f32_16x16x32_bf16(wf[me], itf[nb], acc[me][nb], 0, 0, 0);
  }

  // e_global = eh*128 + w*32 + me*16 + lg*4 + rr ; kc = e>>6, d = e&63
  #pragma unroll
  for (int nb = 0; nb < 4; nb++) {
    const int bb = b0 + nb * 16 + lr;
    const bool live = (mskS[nb * 16 + lr] != 0.f);
    #pragma unroll
    for (int me = 0; me < 2; me++) {
      const int eg = eh * 128 + w * 32 + me * 16;
      const int kc = eg >> 6;
      const int d0 = (eg & 63) + lg * 4;
      if (live) {
        sh4 v;
        v[0] = (short)f2bf(acc[me][nb][0]);
        v[1] = (short)f2bf(acc[me][nb][1]);
        v[2] = (short)f2bf(acc[me][nb][2]);
        v[3] = (short)f2bf(acc[me][nb][3]);
        *(sh4*)(hatb + (((size_t)bb * NI_SZ + kc) * S_SZ + s) * D_SZ + d0) = v;
      }
    }
  }
}

// ---------------- K3: routing; dead-position loads redirected to a hot line (branch-free) ----------------
__device__ __forceinline__ float rlane(float v, int l) {
  return __int_as_float(__builtin_amdgcn_readlane(__float_as_int(v), l));
}

__global__ __launch_bounds__(1024, 4) void route_kernel(
    const u16* __restrict__ hatb, const float* __restrict__ mask,
    float* __restrict__ out)
{
  const int b = blockIdx.x;
  const int t = threadIdx.x;
  const int w = t >> 6, lane = t & 63;
  const int k = w >> 2, q = w & 3;
  __shared__ float cwS[NI_SZ][212];
  __shared__ float partS[NI_SZ][4][D_SZ];

  const float msv = (lane < 50) ? mask[b * S_SZ + q * 50 + lane] : 0.f;

  float hr[50];
  const u16* hg = hatb + (((size_t)b * NI_SZ + k) * S_SZ + q * 50) * D_SZ + lane;
  #pragma unroll
  for (int j = 0; j < 50; j++) {
    const float hm = rlane(msv, j);
    // dead position: load the wave-base line instead (L1/L2-hot, ~free), no branch
    const u16* p = (hm != 0.f) ? (hg + j * D_SZ) : hg;
    const float v = bf2f(*p);
    hr[j] = (hm != 0.f) ? v : 0.f;
  }
  #pragma unroll
  for (int j = 0; j < 50; j++) asm volatile("" : "+v"(hr[j]));

  const int jj = __brev(lane) >> 26;

  for (int iter = 0; iter < 3; ++iter) {
    float swv;
    if (iter == 0) {
      swv = 0.25f * msv;
    } else {
      const int sidx = q * 50 + (lane < 50 ? lane : 49);
      const float a0 = cwS[0][sidx], a1 = cwS[1][sidx],
                  a2 = cwS[2][sidx], a3 = cwS[3][sidx];
      const float mx = fmaxf(fmaxf(a0, a1), fmaxf(a2, a3));
      const float e0 = __expf(a0 - mx), e1 = __expf(a1 - mx),
                  e2 = __expf(a2 - mx), e3 = __expf(a3 - mx);
      const float ek = (k == 0) ? e0 : (k == 1) ? e1 : (k == 2) ? e2 : e3;
      const float inv = 1.f / (e0 + e1 + e2 + e3);
      swv = (msv == 0.f) ? 0.f : ek * inv;
    }

    float c0 = 0.f, c1 = 0.f, c2 = 0.f, c3 = 0.f;
    #pragma unroll
    for (int j = 0; j < 48; j += 4) {
      c0 = fmaf(rlane(swv, j + 0), hr[j + 0], c0);
      c1 = fmaf(rlane(swv, j + 1), hr[j + 1], c1);
      c2 = fmaf(rlane(swv, j + 2), hr[j + 2], c2);
      c3 = fmaf(rlane(swv, j + 3), hr[j + 3], c3);
    }
    c0 = fmaf(rlane(swv, 48), hr[48], c0);
    c1 = fmaf(rlane(swv, 49), hr[49], c1);
    partS[k][q][lane] = (c0 + c2) + (c1 + c3);
    __syncthreads();

    const float cap = partS[k][0][lane] + partS[k][1][lane]
                    + partS[k][2][lane] + partS[k][3][lane];
    float n = cap * cap;
    #pragma unroll
    for (int off = 32; off; off >>= 1) n += __shfl_xor(n, off);
    const float f = n / (1.f + n) * rsqrtf(n + 1e-9f);
    const float capd = cap * f;

    if (iter < 2) {
      float p[32];
      {
        const int bit = lane & 1;
        #pragma unroll
        for (int j = 0; j < 32; j++) {
          const float lo = hr[j] * capd;
          const float hi = (j + 32 < 50) ? hr[j + 32] * capd : 0.f;
          const float send = bit ? lo : hi;
          const float keep = bit ? hi : lo;
          p[j] = keep + __shfl_xor(send, 1);
        }
      }
      #pragma unroll
      for (int rr = 1; rr < 6; rr++) {
        const int dist = 1 << rr;
        const int half = 32 >> rr;
        const int bit = (lane >> rr) & 1;
        #pragma unroll
        for (int j = 0; j < 32; j++) {
          if (j < half) {
            const float send = bit ? p[j] : p[j + half];
            const float keep = bit ? p[j + half] : p[j];
            p[j] = keep + __shfl_xor(send, dist);
          }
        }
      }
      if (jj < 50) {
        if (iter == 0) cwS[k][q * 50 + jj] = p[0];
        else           cwS[k][q * 50 + jj] += p[0];
      }
      __syncthreads();
    } else if (q == 0) {
      out[((size_t)b * NI_SZ + k) * D_SZ + lane] = capd;
    }
  }
}

extern "C" void kernel_launch(void* const* d_in, const int* in_sizes, int n_in,
                              void* d_out, int out_size, void* d_ws, size_t ws_size,
                              hipStream_t stream)
{
  const int*   uid     = (const int*)d_in[0];
  const int*   age     = (const int*)d_in[1];
  const int*   gender  = (const int*)d_in[2];
  const int*   occup   = (const int*)d_in[3];
  const int*   mid_his = (const int*)d_in[4];
  const float* mask    = (const float*)d_in[5];
  const float* U       = (const float*)d_in[6];
  const float* AT      = (const float*)d_in[7];
  const float* GT      = (const float*)d_in[8];
  const float* OT      = (const float*)d_in[9];
  const float* ME      = (const float*)d_in[10];
  const float* WC      = (const float*)d_in[11];

  float* out  = (float*)d_out;
  float* adj  = out + B_SZ * NI_SZ * D_SZ;

  u16* hatb = (u16*)d_ws;                      // 104.9 MB

  adj_kernel<<<B_SZ, 256, 0, stream>>>(uid, age, gender, occup, U, AT, GT, OT,
                                       mid_his, mask, ME, adj);
  hat_kernel<<<6400, 256, 0, stream>>>(mid_his, mask, ME, WC, hatb);
  route_kernel<<<B_SZ, 1024, 0, stream>>>(hatb, mask, out);
}

// Round 13
// 136.025 us; speedup vs baseline: 1.2874x; 1.0021x over previous
//
#include <hip/hip_runtime.h>

#define B_SZ 1024
#define S_SZ 200
#define D_SZ 64
#define NI_SZ 4
#define E_SZ 256

using u16 = unsigned short;
using u32 = unsigned int;
typedef short  sh4    __attribute__((ext_vector_type(4)));
typedef short  sh8    __attribute__((ext_vector_type(8)));
typedef __bf16 bf16x8 __attribute__((ext_vector_type(8)));
typedef float  f32x4  __attribute__((ext_vector_type(4)));

__device__ __forceinline__ u16 f2bf(float x) {          // RNE f32 -> bf16 bits
  u32 u = __float_as_uint(x);
  u += 0x7FFFu + ((u >> 16) & 1u);
  return (u16)(u >> 16);
}
__device__ __forceinline__ float bf2f(u16 h) {
  return __uint_as_float(((u32)h) << 16);
}
// swizzled LDS tile access: row-major [R][64] bf16 (128 B rows), byte ^= (row&7)<<4
__device__ __forceinline__ sh8 ldsr(const u16* arr, int row, int kshort) {
  const int idx = row * 64 + (kshort ^ ((row & 7) << 3));
  return *(const sh8*)(arr + idx);
}
__device__ __forceinline__ bf16x8 ldsw(const u16* arr, int row, int kshort) {
  return __builtin_bit_cast(bf16x8, ldsr(arr, row, kshort));
}
__device__ __forceinline__ void stsw(u16* arr, int row, int c, sh8 v) {
  *(sh8*)(arr + row * 64 + 8 * (c ^ (row & 7))) = v;
}
__device__ __forceinline__ sh8 cvt8(const float* __restrict__ src, float m) {
  const float4 a = *(const float4*)(src);
  const float4 d = *(const float4*)(src + 4);
  sh8 v;
  v[0] = (short)f2bf(a.x * m); v[1] = (short)f2bf(a.y * m);
  v[2] = (short)f2bf(a.z * m); v[3] = (short)f2bf(a.w * m);
  v[4] = (short)f2bf(d.x * m); v[5] = (short)f2bf(d.y * m);
  v[6] = (short)f2bf(d.z * m); v[7] = (short)f2bf(d.w * m);
  return v;
}

// ---------------- K1: adj — fused gather + J-compacted MFMA + LDS-staged dense stores ----------------
__global__ __launch_bounds__(256) void adj_kernel(
    const int* __restrict__ uid, const int* __restrict__ age,
    const int* __restrict__ gender, const int* __restrict__ occup,
    const float* __restrict__ U, const float* __restrict__ AT,
    const float* __restrict__ GT, const float* __restrict__ OT,
    const int* __restrict__ mid_his, const float* __restrict__ mask,
    const float* __restrict__ memb, float* __restrict__ adj)
{
  const int b = blockIdx.x;
  __shared__ u16   Hs[208 * 64];   // 26624 B, swizzled
  __shared__ float Ms[208];
  __shared__ int   midS[S_SZ];
  __shared__ float pS[D_SZ];
  __shared__ u16   liveS[208];     // compacted live j indices (pad 207)
  __shared__ int   Lsh;
  __shared__ float OutS[8 * 212];  // 6784 B output staging (rows pad 212)
  const int tid = threadIdx.x;

  if (tid < 208) Ms[tid] = (tid < S_SZ) ? mask[b * S_SZ + tid] : 0.f;
  if (tid < S_SZ) midS[tid] = mid_his[b * S_SZ + tid];
  if (tid < D_SZ) {
    float v = U[(size_t)uid[b]     * D_SZ + tid]
            + GT[(size_t)gender[b] * D_SZ + tid]
            + AT[(size_t)age[b]    * D_SZ + tid]
            + OT[(size_t)occup[b]  * D_SZ + tid];
    pS[tid] = 0.25f * v;
  }
  if (tid < 208) liveS[tid] = 207;
  for (int i = tid; i < 8 * 212; i += 256) OutS[i] = 0.f;
  __syncthreads();

  // wave 0: order-preserving compaction of live positions (ballot + popc prefix)
  if (tid < 64) {
    int base = 0;
    #pragma unroll
    for (int c = 0; c < 4; c++) {
      const int s = c * 64 + tid;
      const bool live = (s < S_SZ) && (Ms[s] != 0.f);
      const unsigned long long mk = __ballot(live);
      const int pfx = __popcll(mk & ((1ull << tid) - 1ull));
      if (live) liveS[base + pfx] = (u16)s;
      base += (int)__popcll(mk);
    }
    if (tid == 0) Lsh = base;
  }
  // gather live rows -> swizzled Hs (dead rows = zeros)
  for (int idx = tid; idx < S_SZ * 8; idx += 256) {
    const int row = idx >> 3, c = idx & 7;
    const float m = Ms[row];
    sh8 v = {0, 0, 0, 0, 0, 0, 0, 0};
    if (m != 0.f) v = cvt8(memb + (size_t)midS[row] * D_SZ + c * 8, m);
    stsw(Hs, row, c, v);
  }
  if (tid < 64) {   // zero-pad rows 200..207
    sh8 z = {0,0,0,0,0,0,0,0};
    stsw(Hs, S_SZ + (tid >> 3), tid & 7, z);
  }
  __syncthreads();

  const int L   = Lsh;
  const int nTc = (L + 15) >> 4;      // compacted column tiles
  const int w = tid >> 6, l = tid & 63;
  const int lr = l & 15, lg = l >> 4;
  float pvA[8], pvB[8];
  #pragma unroll
  for (int j = 0; j < 8; j++) { pvA[j] = pS[lg * 8 + j]; pvB[j] = pS[32 + lg * 8 + j]; }

  float* outb = adj + (size_t)b * S_SZ * S_SZ;

  for (int mt = 0; mt < 13; mt++) {
    // A fragment (hu = item * prof), original (uncompacted) rows
    const int arow = mt * 16 + lr;
    const sh8 r0 = ldsr(Hs, arow, lg * 8);
    const sh8 r1 = ldsr(Hs, arow, 32 + lg * 8);
    sh8 h0, h1;
    #pragma unroll
    for (int j = 0; j < 8; j++) {
      h0[j] = (short)f2bf(bf2f((u16)r0[j]) * pvA[j]);
      h1[j] = (short)f2bf(bf2f((u16)r1[j]) * pvB[j]);
    }
    const bf16x8 a0 = __builtin_bit_cast(bf16x8, h0);
    const bf16x8 a1 = __builtin_bit_cast(bf16x8, h1);

    float msm[4];
    #pragma unroll
    for (int rr = 0; rr < 4; rr++) msm[rr] = Ms[mt * 16 + lg * 4 + rr];

    // compute up to 4 compacted tiles, sigmoid applied in-place (full-wave trans)
    f32x4 ov[4];
    int   jv[4];
    #pragma unroll
    for (int t = 0; t < 4; t++) {
      const int ntc = w + t * 4;
      jv[t] = 207;
      ov[t] = (f32x4){0.f, 0.f, 0.f, 0.f};
      if (ntc < nTc) {
        const int jr = liveS[ntc * 16 + lr];   // LDS-indirect live row
        jv[t] = jr;
        const bf16x8 b0 = ldsw(Hs, jr, lg * 8);
        const bf16x8 b1 = ldsw(Hs, jr, 32 + lg * 8);
        f32x4 acc = {0.f, 0.f, 0.f, 0.f};
        acc = __builtin_amdgcn_mfma_f32_16x16x32_bf16(a0, b0, acc, 0, 0, 0);
        acc = __builtin_amdgcn_mfma_f32_16x16x32_bf16(a1, b1, acc, 0, 0, 0);
        const float mj = Ms[jr];
        #pragma unroll
        for (int rr = 0; rr < 4; rr++) {
          const float sg = 1.f / (1.f + __expf(-acc[rr]));
          ov[t][rr] = sg * msm[rr] * mj;
        }
      }
    }

    // two half-row dumps: scatter -> barrier -> dense stream + rezero -> barrier
    #pragma unroll
    for (int h = 0; h < 2; h++) {
      if ((lg >> 1) == h) {
        #pragma unroll
        for (int t = 0; t < 4; t++) {
          if (w + t * 4 < nTc) {
            #pragma unroll
            for (int rr = 0; rr < 4; rr++)
              OutS[((lg & 1) * 4 + rr) * 212 + jv[t]] = ov[t][rr];
          }
        }
      }
      __syncthreads();
      const int rowbase = mt * 16 + h * 8;
      if (rowbase < S_SZ) {
        for (int c = tid; c < 400; c += 256) {   // 8 rows x 50 float4 = contiguous 6400 B
          const int r = c / 50, cc = (c % 50) * 4;
          float4* ls = (float4*)&OutS[r * 212 + cc];
          const float4 v = *ls;
          *(float4*)&outb[(size_t)(rowbase + r) * S_SZ + cc] = v;
          *ls = make_float4(0.f, 0.f, 0.f, 0.f);
        }
      }
      __syncthreads();
    }
  }
}

// ---------------- K2: hat via MFMA (A=W, B=item), e-split halves, masked-store skip ----------------
__global__ __launch_bounds__(256, 6) void hat_kernel(
    const int* __restrict__ mid_his, const float* __restrict__ mask,
    const float* __restrict__ memb, const float* __restrict__ WC,
    u16* __restrict__ hatb)
{
  // bid = t*256 + x*16 + eh*8 + r ; s = t*8 + r (32 blocks sharing s sit on one XCD)
  const int bid = blockIdx.x;
  const int s  = (bid >> 8) * 8 + (bid & 7);   // [0,200)
  const int eh = (bid >> 3) & 1;               // e-half
  const int b0 = ((bid >> 4) & 15) * 64;
  __shared__ u16 As[64 * 64];      // item rows, 8 KB
  __shared__ u16 Ws_[128 * 64];    // W[s] half, 16 KB
  __shared__ float mskS[64];
  const int tid = threadIdx.x;

  for (int idx = tid; idx < 64 * 8; idx += 256) {
    const int row = idx >> 3, c = idx & 7;
    const int bb = b0 + row;
    const float m = mask[bb * S_SZ + s];
    if (c == 0) mskS[row] = m;
    sh8 v = {0, 0, 0, 0, 0, 0, 0, 0};
    if (m != 0.f)
      v = cvt8(memb + (size_t)mid_his[bb * S_SZ + s] * D_SZ + c * 8, m);
    stsw(As, row, c, v);
  }
  for (int idx = tid; idx < 128 * 8; idx += 256) {
    const int row = idx >> 3, c = idx & 7;
    stsw(Ws_, row, c, cvt8(WC + ((size_t)s * E_SZ + eh * 128 + row) * D_SZ + c * 8, 1.f));
  }
  __syncthreads();

  const int w = tid >> 6, l = tid & 63;
  const int lr = l & 15, lg = l >> 4;

  f32x4 acc[2][4];                 // [me][nb]
  #pragma unroll
  for (int me = 0; me < 2; me++)
    #pragma unroll
    for (int nb = 0; nb < 4; nb++) acc[me][nb] = (f32x4){0.f, 0.f, 0.f, 0.f};

  #pragma unroll
  for (int ks = 0; ks < 2; ks++) {
    bf16x8 wf[2], itf[4];
    #pragma unroll
    for (int me = 0; me < 2; me++)
      wf[me] = ldsw(Ws_, w * 32 + me * 16 + lr, ks * 32 + lg * 8);
    #pragma unroll
    for (int nb = 0; nb < 4; nb++)
      itf[nb] = ldsw(As, nb * 16 + lr, ks * 32 + lg * 8);
    #pragma unroll
    for (int me = 0; me < 2; me++)
      #pragma unroll
      for (int nb = 0; nb < 4; nb++)
        acc[me][nb] = __builtin_amdgcn_mfma_f32_16x16x32_bf16(wf[me], itf[nb], acc[me][nb], 0, 0, 0);
  }

  // e_global = eh*128 + w*32 + me*16 + lg*4 + rr ; kc = e>>6, d = e&63
  #pragma unroll
  for (int nb = 0; nb < 4; nb++) {
    const int bb = b0 + nb * 16 + lr;
    const bool live = (mskS[nb * 16 + lr] != 0.f);
    #pragma unroll
    for (int me = 0; me < 2; me++) {
      const int eg = eh * 128 + w * 32 + me * 16;
      const int kc = eg >> 6;
      const int d0 = (eg & 63) + lg * 4;
      if (live) {
        sh4 v;
        v[0] = (short)f2bf(acc[me][nb][0]);
        v[1] = (short)f2bf(acc[me][nb][1]);
        v[2] = (short)f2bf(acc[me][nb][2]);
        v[3] = (short)f2bf(acc[me][nb][3]);
        *(sh4*)(hatb + (((size_t)bb * NI_SZ + kc) * S_SZ + s) * D_SZ + d0) = v;
      }
    }
  }
}

// ---------------- K3: routing; dead-position loads redirected to a hot line (branch-free) ----------------
__device__ __forceinline__ float rlane(float v, int l) {
  return __int_as_float(__builtin_amdgcn_readlane(__float_as_int(v), l));
}

__global__ __launch_bounds__(1024, 4) void route_kernel(
    const u16* __restrict__ hatb, const float* __restrict__ mask,
    float* __restrict__ out)
{
  const int b = blockIdx.x;
  const int t = threadIdx.x;
  const int w = t >> 6, lane = t & 63;
  const int k = w >> 2, q = w & 3;
  __shared__ float cwS[NI_SZ][212];
  __shared__ float partS[NI_SZ][4][D_SZ];

  const float msv = (lane < 50) ? mask[b * S_SZ + q * 50 + lane] : 0.f;

  float hr[50];
  const u16* hg = hatb + (((size_t)b * NI_SZ + k) * S_SZ + q * 50) * D_SZ + lane;
  #pragma unroll
  for (int j = 0; j < 50; j++) {
    const float hm = rlane(msv, j);
    // dead position: load the wave-base line instead (L1/L2-hot, ~free), no branch
    const u16* p = (hm != 0.f) ? (hg + j * D_SZ) : hg;
    const float v = bf2f(*p);
    hr[j] = (hm != 0.f) ? v : 0.f;
  }
  #pragma unroll
  for (int j = 0; j < 50; j++) asm volatile("" : "+v"(hr[j]));

  const int jj = __brev(lane) >> 26;

  for (int iter = 0; iter < 3; ++iter) {
    float swv;
    if (iter == 0) {
      swv = 0.25f * msv;
    } else {
      const int sidx = q * 50 + (lane < 50 ? lane : 49);
      const float a0 = cwS[0][sidx], a1 = cwS[1][sidx],
                  a2 = cwS[2][sidx], a3 = cwS[3][sidx];
      const float mx = fmaxf(fmaxf(a0, a1), fmaxf(a2, a3));
      const float e0 = __expf(a0 - mx), e1 = __expf(a1 - mx),
                  e2 = __expf(a2 - mx), e3 = __expf(a3 - mx);
      const float ek = (k == 0) ? e0 : (k == 1) ? e1 : (k == 2) ? e2 : e3;
      const float inv = 1.f / (e0 + e1 + e2 + e3);
      swv = (msv == 0.f) ? 0.f : ek * inv;
    }

    float c0 = 0.f, c1 = 0.f, c2 = 0.f, c3 = 0.f;
    #pragma unroll
    for (int j = 0; j < 48; j += 4) {
      c0 = fmaf(rlane(swv, j + 0), hr[j + 0], c0);
      c1 = fmaf(rlane(swv, j + 1), hr[j + 1], c1);
      c2 = fmaf(rlane(swv, j + 2), hr[j + 2], c2);
      c3 = fmaf(rlane(swv, j + 3), hr[j + 3], c3);
    }
    c0 = fmaf(rlane(swv, 48), hr[48], c0);
    c1 = fmaf(rlane(swv, 49), hr[49], c1);
    partS[k][q][lane] = (c0 + c2) + (c1 + c3);
    __syncthreads();

    const float cap = partS[k][0][lane] + partS[k][1][lane]
                    + partS[k][2][lane] + partS[k][3][lane];
    float n = cap * cap;
    #pragma unroll
    for (int off = 32; off; off >>= 1) n += __shfl_xor(n, off);
    const float f = n / (1.f + n) * rsqrtf(n + 1e-9f);
    const float capd = cap * f;

    if (iter < 2) {
      float p[32];
      {
        const int bit = lane & 1;
        #pragma unroll
        for (int j = 0; j < 32; j++) {
          const float lo = hr[j] * capd;
          const float hi = (j + 32 < 50) ? hr[j + 32] * capd : 0.f;
          const float send = bit ? lo : hi;
          const float keep = bit ? hi : lo;
          p[j] = keep + __shfl_xor(send, 1);
        }
      }
      #pragma unroll
      for (int rr = 1; rr < 6; rr++) {
        const int dist = 1 << rr;
        const int half = 32 >> rr;
        const int bit = (lane >> rr) & 1;
        #pragma unroll
        for (int j = 0; j < 32; j++) {
          if (j < half) {
            const float send = bit ? p[j] : p[j + half];
            const float keep = bit ? p[j + half] : p[j];
            p[j] = keep + __shfl_xor(send, dist);
          }
        }
      }
      if (jj < 50) {
        if (iter == 0) cwS[k][q * 50 + jj] = p[0];
        else           cwS[k][q * 50 + jj] += p[0];
      }
      __syncthreads();
    } else if (q == 0) {
      out[((size_t)b * NI_SZ + k) * D_SZ + lane] = capd;
    }
  }
}

extern "C" void kernel_launch(void* const* d_in, const int* in_sizes, int n_in,
                              void* d_out, int out_size, void* d_ws, size_t ws_size,
                              hipStream_t stream)
{
  const int*   uid     = (const int*)d_in[0];
  const int*   age     = (const int*)d_in[1];
  const int*   gender  = (const int*)d_in[2];
  const int*   occup   = (const int*)d_in[3];
  const int*   mid_his = (const int*)d_in[4];
  const float* mask    = (const float*)d_in[5];
  const float* U       = (const float*)d_in[6];
  const float* AT      = (const float*)d_in[7];
  const float* GT      = (const float*)d_in[8];
  const float* OT      = (const float*)d_in[9];
  const float* ME      = (const float*)d_in[10];
  const float* WC      = (const float*)d_in[11];

  float* out  = (float*)d_out;
  float* adj  = out + B_SZ * NI_SZ * D_SZ;

  u16* hatb = (u16*)d_ws;                      // 104.9 MB

  adj_kernel<<<B_SZ, 256, 0, stream>>>(uid, age, gender, occup, U, AT, GT, OT,
                                       mid_his, mask, ME, adj);
  hat_kernel<<<6400, 256, 0, stream>>>(mid_his, mask, ME, WC, hatb);
  route_kernel<<<B_SZ, 1024, 0, stream>>>(hatb, mask, out);
}